// Round 3
// baseline (225.216 us; speedup 1.0000x reference)
//
#include <hip/hip_runtime.h>

typedef __bf16 bf16x8 __attribute__((ext_vector_type(8)));
typedef float f32x4 __attribute__((ext_vector_type(4)));

#define G_N 2000
#define K_N 64
#define DEG_INN 8
#define DEG_EXTN 16
#define B_N 1024
#define D 128

__device__ __forceinline__ float bflo(unsigned int u) { return __uint_as_float(u << 16); }
__device__ __forceinline__ float bfhi(unsigned int u) { return __uint_as_float(u & 0xffff0000u); }
__device__ __forceinline__ unsigned short f2bf(float f) {
  unsigned int u = __float_as_uint(f);
  u += 0x7fffu + ((u >> 16) & 1u);
  return (unsigned short)(u >> 16);
}
__device__ __forceinline__ unsigned int pack2bf(float lo, float hi) {
  return ((unsigned int)f2bf(hi) << 16) | (unsigned int)f2bf(lo);
}

// ---------------- K1: gather + dual GEMM (K-split) + relu + reduce + softmax --
// 1 graph / block, 256 threads (4 waves). f32 inputs; bf16 LDS tiles for MFMA.
constexpr int LD1 = 136;  // 128 + 8 bf16 pad

__global__ __launch_bounds__(256)
void k1_msg(const int* __restrict__ node_type, const int* __restrict__ nbr_type,
            const float* __restrict__ impact,
            const float* __restrict__ Wm, const float* __restrict__ Mm,
            float* __restrict__ E)
{
  __shared__ __align__(16) unsigned short Bs[128 * LD1];  // 34816 B
  __shared__ __align__(16) unsigned short As[64 * LD1];   // 17408 B
  __shared__ float red[4 * 128];
  __shared__ float pg[128];

  const int g    = blockIdx.x;
  const int tid  = threadIdx.x;
  const int wave = tid >> 6, lane = tid & 63;

  f32x4 acc[8];
  #pragma unroll
  for (int n = 0; n < 8; ++n) acc[n] = (f32x4){0.f, 0.f, 0.f, 0.f};

  const int qk   = (lane >> 4) * 8;
  const int arow = wave * 16 + (lane & 15);

  #pragma unroll
  for (int pass = 0; pass < 2; ++pass) {
    // stage Bs = bf16( (pass ? M : W)[0..127][0..127] )
    const float* Bsrc = pass ? Mm : Wm;
    for (int i = tid; i < 128 * 32; i += 256) {       // 32 float4-chunks per row
      int row = i >> 5, c4 = i & 31;
      float4 v = ((const float4*)Bsrc)[row * 32 + c4];
      unsigned int p0 = pack2bf(v.x, v.y), p1 = pack2bf(v.z, v.w);
      *(unsigned int*)(Bs + row * LD1 + c4 * 4)     = p0;
      *(unsigned int*)(Bs + row * LD1 + c4 * 4 + 2) = p1;
    }
    // stage As rows (bf16)
    if (pass == 0) {
      for (int rr = 0; rr < 16; ++rr) {
        int r  = wave * 16 + rr;
        int nt = node_type[g * K_N + r];
        float2 v = ((const float2*)(impact + (size_t)nt * D))[lane];
        *(unsigned int*)(As + r * LD1 + lane * 2) = pack2bf(v.x, v.y);
      }
    } else {
      for (int rr = 0; rr < 16; ++rr) {
        int r = wave * 16 + rr;
        const int* nb = nbr_type + (size_t)(g * K_N + r) * DEG_INN;
        float a0 = 0.f, a1 = 0.f;
        #pragma unroll
        for (int d = 0; d < DEG_INN; ++d) {
          float2 v = ((const float2*)(impact + (size_t)nb[d] * D))[lane];
          a0 += v.x; a1 += v.y;
        }
        *(unsigned int*)(As + r * LD1 + lane * 2) = pack2bf(a0, a1);
      }
    }
    __syncthreads();

    // MFMA: this wave's 16 rows x 128 cols, K = 128 this pass
    #pragma unroll
    for (int kk = 0; kk < 4; ++kk) {
      bf16x8 af = *(const bf16x8*)(As + arow * LD1 + kk * 32 + qk);
      #pragma unroll
      for (int n = 0; n < 8; ++n) {
        bf16x8 bfr = *(const bf16x8*)(Bs + (n * 16 + (lane & 15)) * LD1 + kk * 32 + qk);
        acc[n] = __builtin_amdgcn_mfma_f32_16x16x32_bf16(af, bfr, acc[n], 0, 0, 0);
      }
    }
    __syncthreads();
  }

  // relu + sum this wave's 16 rows; C/D: col=lane&15, row=quad*4+reg
  #pragma unroll
  for (int n = 0; n < 8; ++n) {
    float cs = fmaxf(acc[n][0], 0.f) + fmaxf(acc[n][1], 0.f)
             + fmaxf(acc[n][2], 0.f) + fmaxf(acc[n][3], 0.f);
    cs += __shfl_xor(cs, 16, 64);
    cs += __shfl_xor(cs, 32, 64);
    if (lane < 16) red[wave * 128 + n * 16 + lane] = cs;
  }
  __syncthreads();

  if (tid < 128)
    pg[tid] = red[tid] + red[128 + tid] + red[256 + tid] + red[384 + tid];
  __syncthreads();

  if (wave == 0) {
    float v0 = pg[lane], v1 = pg[64 + lane];
    float mx = fmaxf(v0, v1);
    #pragma unroll
    for (int o = 32; o; o >>= 1) mx = fmaxf(mx, __shfl_xor(mx, o, 64));
    float e0 = __expf(v0 - mx), e1 = __expf(v1 - mx);
    float s = e0 + e1;
    #pragma unroll
    for (int o = 32; o; o >>= 1) s += __shfl_xor(s, o, 64);
    float inv = 1.f / s;
    E[(size_t)g * D + lane]      = e0 * inv;
    E[(size_t)g * D + 64 + lane] = e1 * inv;
  }
}

// ---------------- K3: ext = E@U^T + Esum@V^T ; X = softmax(relu(ext)) --------
__global__ __launch_bounds__(256)
void k3_ext(const int* __restrict__ ext_nbr, const float* __restrict__ E,
            const float* __restrict__ U, const float* __restrict__ V,
            float* __restrict__ X)
{
  __shared__ float Ev[128], Es[128], part[256], scr[8];

  const int tid = threadIdx.x;
  const int j = tid & 127, kh = tid >> 7;
  const int lane = tid & 63, wv = tid >> 6;

  unsigned int Ur[32], Vr[32];  // bf16-packed U[j][kh*64..+64), V[j][...]
  #pragma unroll
  for (int c = 0; c < 32; ++c) {
    float2 u2 = ((const float2*)(U + (size_t)j * D + kh * 64))[c];
    float2 v2 = ((const float2*)(V + (size_t)j * D + kh * 64))[c];
    Ur[c] = pack2bf(u2.x, u2.y);
    Vr[c] = pack2bf(v2.x, v2.y);
  }

  for (int it = 0; it < 8; ++it) {
    const int g = blockIdx.x * 8 + it;
    if (kh == 0) {
      Ev[j] = E[(size_t)g * D + j];
    } else {
      float a = 0.f;
      const int* en = ext_nbr + (size_t)g * DEG_EXTN;
      #pragma unroll
      for (int d = 0; d < DEG_EXTN; ++d) a += E[(size_t)en[d] * D + j];
      Es[j] = a;
    }
    __syncthreads();

    float s = 0.f;
    #pragma unroll
    for (int c = 0; c < 32; ++c) {
      s += bflo(Ur[c]) * Ev[kh * 64 + 2 * c] + bfhi(Ur[c]) * Ev[kh * 64 + 2 * c + 1]
         + bflo(Vr[c]) * Es[kh * 64 + 2 * c] + bfhi(Vr[c]) * Es[kh * 64 + 2 * c + 1];
    }
    part[tid] = s;
    __syncthreads();

    float r = 0.f, e = 0.f;
    if (tid < 128) {
      r = fmaxf(part[tid] + part[128 + tid], 0.f);
      float mx = r;
      #pragma unroll
      for (int o = 32; o; o >>= 1) mx = fmaxf(mx, __shfl_xor(mx, o, 64));
      if (lane == 0) scr[wv] = mx;
    }
    __syncthreads();
    if (tid < 128) {
      float mx = fmaxf(scr[0], scr[1]);
      e = __expf(r - mx);
      float sm = e;
      #pragma unroll
      for (int o = 32; o; o >>= 1) sm += __shfl_xor(sm, o, 64);
      if (lane == 0) scr[4 + wv] = sm;
    }
    __syncthreads();
    if (tid < 128) X[(size_t)g * D + tid] = e / (scr[4] + scr[5]);
    __syncthreads();
  }
}

// ---------------- K4: final MLP + 2-way softmax ------------------------------
__global__ __launch_bounds__(256)
void k4_mlp(const int* __restrict__ batch, const float* __restrict__ Xv,
            const float* __restrict__ W1, const float* __restrict__ b1,
            const float* __restrict__ W2, const float* __restrict__ b2,
            float* __restrict__ out)
{
  __shared__ float feat[256], hp[256], hv[128], scr[2];

  const int tid = threadIdx.x;
  const int j = tid & 127, kh = tid >> 7;
  const int lane = tid & 63, wv = tid >> 6;

  unsigned int W1r[64];  // bf16-packed W1[j][kh*128 .. +128)
  #pragma unroll
  for (int c = 0; c < 64; ++c) {
    float2 w2 = ((const float2*)(W1 + (size_t)j * 256 + kh * 128))[c];
    W1r[c] = pack2bf(w2.x, w2.y);
  }

  for (int it = 0; it < 8; ++it) {
    const int b = blockIdx.x * 8 + it;
    const int i1 = batch[2 * b], i2 = batch[2 * b + 1];
    if (tid < 128) {
      float e1 = Xv[(size_t)i1 * D + tid], e2 = Xv[(size_t)i2 * D + tid];
      feat[tid]       = e1 * e2;
      feat[128 + tid] = e1 + e2;
    }
    __syncthreads();

    float s = 0.f;
    #pragma unroll
    for (int c = 0; c < 64; ++c)
      s += bflo(W1r[c]) * feat[kh * 128 + 2 * c] + bfhi(W1r[c]) * feat[kh * 128 + 2 * c + 1];
    hp[tid] = s;
    __syncthreads();
    if (tid < 128) hv[tid] = fmaxf(hp[tid] + hp[128 + tid] + b1[tid], 0.f);
    __syncthreads();

    if (wv < 2) {
      float p = W2[wv * 128 + lane] * hv[lane]
              + W2[wv * 128 + 64 + lane] * hv[64 + lane];
      #pragma unroll
      for (int o = 32; o; o >>= 1) p += __shfl_xor(p, o, 64);
      if (lane == 0) scr[wv] = p + b2[wv];
    }
    __syncthreads();
    if (tid == 0) {
      float r0 = scr[0], r1 = scr[1];
      float m = fmaxf(r0, r1);
      float q0 = __expf(r0 - m), q1 = __expf(r1 - m);
      float inv = 1.f / (q0 + q1);
      out[2 * b]     = q0 * inv;
      out[2 * b + 1] = q1 * inv;
    }
    __syncthreads();
  }
}

// ---------------- launch -----------------------------------------------------
extern "C" void kernel_launch(void* const* d_in, const int* in_sizes, int n_in,
                              void* d_out, int out_size, void* d_ws, size_t ws_size,
                              hipStream_t stream) {
  const int* batch     = (const int*)d_in[0];
  const int* node_type = (const int*)d_in[1];
  const int* nbr_type  = (const int*)d_in[2];
  const int* ext_nbr   = (const int*)d_in[3];
  const float* impact  = (const float*)d_in[4];
  const float* W       = (const float*)d_in[5];
  const float* M       = (const float*)d_in[6];
  const float* U       = (const float*)d_in[7];
  const float* V       = (const float*)d_in[8];
  const float* W1      = (const float*)d_in[9];
  const float* b1      = (const float*)d_in[10];
  const float* W2      = (const float*)d_in[11];
  const float* b2      = (const float*)d_in[12];
  float* out           = (float*)d_out;

  float* E = (float*)d_ws;                 // 2000*128 f32
  float* X = E + (size_t)G_N * D;          // 2000*128 f32

  k1_msg<<<G_N, 256, 0, stream>>>(node_type, nbr_type, impact, W, M, E);
  k3_ext<<<G_N / 8, 256, 0, stream>>>(ext_nbr, E, U, V, X);
  k4_mlp<<<B_N / 8, 256, 0, stream>>>(batch, X, W1, b1, W2, b2, out);
}

// Round 4
// 152.587 us; speedup vs baseline: 1.4760x; 1.4760x over previous
//
#include <hip/hip_runtime.h>

typedef __bf16 bf16x8 __attribute__((ext_vector_type(8)));
typedef float f32x4 __attribute__((ext_vector_type(4)));

#define G_N 2000
#define K_N 64
#define DEG_INN 8
#define DEG_EXTN 16
#define B_N 1024
#define D 128
#define NT_N 10000

__device__ __forceinline__ float bflo(unsigned int u) { return __uint_as_float(u << 16); }
__device__ __forceinline__ float bfhi(unsigned int u) { return __uint_as_float(u & 0xffff0000u); }
__device__ __forceinline__ unsigned short f2bf(float f) {
  unsigned int u = __float_as_uint(f);
  u += 0x7fffu + ((u >> 16) & 1u);
  return (unsigned short)(u >> 16);
}
__device__ __forceinline__ unsigned int pack2bf(float lo, float hi) {
  return ((unsigned int)f2bf(hi) << 16) | (unsigned int)f2bf(lo);
}

// ---------------- K0: P = impact@W^T, Q = impact@M^T (bf16 out) --------------
// grid (157, 2): y=0 -> P (weights W), y=1 -> Q (weights M). 64 impact rows/block.
constexpr int LD1 = 136;  // bf16 row pad

__global__ __launch_bounds__(256)
void k0_pq(const float* __restrict__ impact,
           const float* __restrict__ Wm, const float* __restrict__ Mm,
           unsigned int* __restrict__ P, unsigned int* __restrict__ Q)
{
  __shared__ __align__(16) unsigned short Bs[128 * LD1];  // 34816 B
  __shared__ __align__(16) unsigned short As[64 * LD1];   // 17408 B

  const int rowbase = blockIdx.x * 64;
  const float* Bsrc = blockIdx.y ? Mm : Wm;
  unsigned int* dst = blockIdx.y ? Q : P;

  const int tid  = threadIdx.x;
  const int wave = tid >> 6, lane = tid & 63;

  // stage weights (128x128 f32 -> bf16)
  for (int i = tid; i < 128 * 32; i += 256) {
    int row = i >> 5, c4 = i & 31;
    float4 v = ((const float4*)Bsrc)[row * 32 + c4];
    *(unsigned int*)(Bs + row * LD1 + c4 * 4)     = pack2bf(v.x, v.y);
    *(unsigned int*)(Bs + row * LD1 + c4 * 4 + 2) = pack2bf(v.z, v.w);
  }
  // stage 64 impact rows (clamped)
  for (int i = tid; i < 64 * 32; i += 256) {
    int r = i >> 5, c4 = i & 31;
    int gr = rowbase + r; if (gr > NT_N - 1) gr = NT_N - 1;
    float4 v = ((const float4*)impact)[(size_t)gr * 32 + c4];
    *(unsigned int*)(As + r * LD1 + c4 * 4)     = pack2bf(v.x, v.y);
    *(unsigned int*)(As + r * LD1 + c4 * 4 + 2) = pack2bf(v.z, v.w);
  }
  __syncthreads();

  f32x4 acc[8];
  #pragma unroll
  for (int n = 0; n < 8; ++n) acc[n] = (f32x4){0.f, 0.f, 0.f, 0.f};
  const int qk   = (lane >> 4) * 8;
  const int arow = wave * 16 + (lane & 15);
  #pragma unroll
  for (int kk = 0; kk < 4; ++kk) {
    bf16x8 af = *(const bf16x8*)(As + arow * LD1 + kk * 32 + qk);
    #pragma unroll
    for (int n = 0; n < 8; ++n) {
      bf16x8 bfr = *(const bf16x8*)(Bs + (n * 16 + (lane & 15)) * LD1 + kk * 32 + qk);
      acc[n] = __builtin_amdgcn_mfma_f32_16x16x32_bf16(af, bfr, acc[n], 0, 0, 0);
    }
  }
  __syncthreads();

  // repack C (col=lane&15, row=(lane>>4)*4+reg) into As as bf16 rows
  const int quad = lane >> 4, c = lane & 15;
  #pragma unroll
  for (int n = 0; n < 8; ++n)
    #pragma unroll
    for (int reg = 0; reg < 4; ++reg)
      As[(wave * 16 + quad * 4 + reg) * LD1 + n * 16 + c] = f2bf(acc[n][reg]);
  __syncthreads();

  // coalesced packed write: row = 64 uints
  for (int i = tid; i < 64 * 32; i += 256) {
    int r = i >> 5, cc = i & 31;
    int gr = rowbase + r;
    if (gr < NT_N)
      dst[(size_t)gr * 64 + cc * 2]     = *(unsigned int*)(As + r * LD1 + cc * 4),
      dst[(size_t)gr * 64 + cc * 2 + 1] = *(unsigned int*)(As + r * LD1 + cc * 4 + 2);
  }
}

// ---------------- K1b: pure gather-relu-reduce + softmax -> E ----------------
// 1 graph / block, 256 thr. Row slot: 16 lanes x uint4 (8 bf16 cols each).
__global__ __launch_bounds__(256)
void k1_gather(const int* __restrict__ node_type, const int* __restrict__ nbr_type,
               const uint4* __restrict__ P, const uint4* __restrict__ Q,
               float* __restrict__ E)
{
  __shared__ float rg[16][132];
  __shared__ float pg[128];

  const int g    = blockIdx.x;
  const int tid  = threadIdx.x;
  const int wave = tid >> 6, lane = tid & 63;
  const int slot = lane >> 4, cl = lane & 15;   // cols cl*8 .. cl*8+7

  float acc[8];
  #pragma unroll
  for (int i = 0; i < 8; ++i) acc[i] = 0.f;

  for (int it = 0; it < 4; ++it) {
    const int r  = wave * 16 + it * 4 + slot;
    const int nt = node_type[g * K_N + r];
    const int* nb = nbr_type + (size_t)(g * K_N + r) * DEG_INN;

    uint4 sv = P[(size_t)nt * 16 + cl];
    float rv[8];
    rv[0] = bflo(sv.x); rv[1] = bfhi(sv.x); rv[2] = bflo(sv.y); rv[3] = bfhi(sv.y);
    rv[4] = bflo(sv.z); rv[5] = bfhi(sv.z); rv[6] = bflo(sv.w); rv[7] = bfhi(sv.w);
    #pragma unroll
    for (int d = 0; d < DEG_INN; ++d) {
      uint4 qv = Q[(size_t)nb[d] * 16 + cl];
      rv[0] += bflo(qv.x); rv[1] += bfhi(qv.x); rv[2] += bflo(qv.y); rv[3] += bfhi(qv.y);
      rv[4] += bflo(qv.z); rv[5] += bfhi(qv.z); rv[6] += bflo(qv.w); rv[7] += bfhi(qv.w);
    }
    #pragma unroll
    for (int i = 0; i < 8; ++i) acc[i] += fmaxf(rv[i], 0.f);
  }

  const int grp = wave * 4 + slot;
  #pragma unroll
  for (int i = 0; i < 8; ++i) rg[grp][cl * 8 + i] = acc[i];
  __syncthreads();

  if (tid < 128) {
    float s = 0.f;
    #pragma unroll
    for (int q = 0; q < 16; ++q) s += rg[q][tid];
    pg[tid] = s;
  }
  __syncthreads();

  if (wave == 0) {
    float v0 = pg[lane], v1 = pg[64 + lane];
    float mx = fmaxf(v0, v1);
    #pragma unroll
    for (int o = 32; o; o >>= 1) mx = fmaxf(mx, __shfl_xor(mx, o, 64));
    float e0 = __expf(v0 - mx), e1 = __expf(v1 - mx);
    float s = e0 + e1;
    #pragma unroll
    for (int o = 32; o; o >>= 1) s += __shfl_xor(s, o, 64);
    float inv = 1.f / s;
    E[(size_t)g * D + lane]      = e0 * inv;
    E[(size_t)g * D + 64 + lane] = e1 * inv;
  }
}

// ---------------- K3: ext = E@U^T + Esum@V^T ; X = softmax(relu(ext)) --------
__global__ __launch_bounds__(256)
void k3_ext(const int* __restrict__ ext_nbr, const float* __restrict__ E,
            const float* __restrict__ U, const float* __restrict__ V,
            float* __restrict__ X)
{
  __shared__ float Ev[128], Es[128], part[256], scr[8];

  const int tid = threadIdx.x;
  const int j = tid & 127, kh = tid >> 7;
  const int lane = tid & 63, wv = tid >> 6;

  unsigned int Ur[32], Vr[32];
  #pragma unroll
  for (int c = 0; c < 32; ++c) {
    float2 u2 = ((const float2*)(U + (size_t)j * D + kh * 64))[c];
    float2 v2 = ((const float2*)(V + (size_t)j * D + kh * 64))[c];
    Ur[c] = pack2bf(u2.x, u2.y);
    Vr[c] = pack2bf(v2.x, v2.y);
  }

  for (int it = 0; it < 2; ++it) {
    const int g = blockIdx.x * 2 + it;
    if (kh == 0) {
      Ev[j] = E[(size_t)g * D + j];
    } else {
      float a = 0.f;
      const int* en = ext_nbr + (size_t)g * DEG_EXTN;
      #pragma unroll
      for (int d = 0; d < DEG_EXTN; ++d) a += E[(size_t)en[d] * D + j];
      Es[j] = a;
    }
    __syncthreads();

    float s = 0.f;
    #pragma unroll
    for (int c = 0; c < 32; ++c) {
      s += bflo(Ur[c]) * Ev[kh * 64 + 2 * c] + bfhi(Ur[c]) * Ev[kh * 64 + 2 * c + 1]
         + bflo(Vr[c]) * Es[kh * 64 + 2 * c] + bfhi(Vr[c]) * Es[kh * 64 + 2 * c + 1];
    }
    part[tid] = s;
    __syncthreads();

    float r = 0.f, e = 0.f;
    if (tid < 128) {
      r = fmaxf(part[tid] + part[128 + tid], 0.f);
      float mx = r;
      #pragma unroll
      for (int o = 32; o; o >>= 1) mx = fmaxf(mx, __shfl_xor(mx, o, 64));
      if (lane == 0) scr[wv] = mx;
    }
    __syncthreads();
    if (tid < 128) {
      float mx = fmaxf(scr[0], scr[1]);
      e = __expf(r - mx);
      float sm = e;
      #pragma unroll
      for (int o = 32; o; o >>= 1) sm += __shfl_xor(sm, o, 64);
      if (lane == 0) scr[4 + wv] = sm;
    }
    __syncthreads();
    if (tid < 128) X[(size_t)g * D + tid] = e / (scr[4] + scr[5]);
    __syncthreads();
  }
}

// ---------------- K4: final MLP + 2-way softmax ------------------------------
__global__ __launch_bounds__(256)
void k4_mlp(const int* __restrict__ batch, const float* __restrict__ Xv,
            const float* __restrict__ W1, const float* __restrict__ b1,
            const float* __restrict__ W2, const float* __restrict__ b2,
            float* __restrict__ out)
{
  __shared__ float feat[256], hp[256], hv[128], scr[2];

  const int tid = threadIdx.x;
  const int j = tid & 127, kh = tid >> 7;
  const int lane = tid & 63, wv = tid >> 6;

  unsigned int W1r[64];
  #pragma unroll
  for (int c = 0; c < 64; ++c) {
    float2 w2 = ((const float2*)(W1 + (size_t)j * 256 + kh * 128))[c];
    W1r[c] = pack2bf(w2.x, w2.y);
  }

  for (int it = 0; it < 2; ++it) {
    const int b = blockIdx.x * 2 + it;
    const int i1 = batch[2 * b], i2 = batch[2 * b + 1];
    if (tid < 128) {
      float e1 = Xv[(size_t)i1 * D + tid], e2 = Xv[(size_t)i2 * D + tid];
      feat[tid]       = e1 * e2;
      feat[128 + tid] = e1 + e2;
    }
    __syncthreads();

    float s = 0.f;
    #pragma unroll
    for (int c = 0; c < 64; ++c)
      s += bflo(W1r[c]) * feat[kh * 128 + 2 * c] + bfhi(W1r[c]) * feat[kh * 128 + 2 * c + 1];
    hp[tid] = s;
    __syncthreads();
    if (tid < 128) hv[tid] = fmaxf(hp[tid] + hp[128 + tid] + b1[tid], 0.f);
    __syncthreads();

    if (wv < 2) {
      float p = W2[wv * 128 + lane] * hv[lane]
              + W2[wv * 128 + 64 + lane] * hv[64 + lane];
      #pragma unroll
      for (int o = 32; o; o >>= 1) p += __shfl_xor(p, o, 64);
      if (lane == 0) scr[wv] = p + b2[wv];
    }
    __syncthreads();
    if (tid == 0) {
      float r0 = scr[0], r1 = scr[1];
      float m = fmaxf(r0, r1);
      float q0 = __expf(r0 - m), q1 = __expf(r1 - m);
      float inv = 1.f / (q0 + q1);
      out[2 * b]     = q0 * inv;
      out[2 * b + 1] = q1 * inv;
    }
    __syncthreads();
  }
}

// ---------------- launch -----------------------------------------------------
extern "C" void kernel_launch(void* const* d_in, const int* in_sizes, int n_in,
                              void* d_out, int out_size, void* d_ws, size_t ws_size,
                              hipStream_t stream) {
  const int* batch     = (const int*)d_in[0];
  const int* node_type = (const int*)d_in[1];
  const int* nbr_type  = (const int*)d_in[2];
  const int* ext_nbr   = (const int*)d_in[3];
  const float* impact  = (const float*)d_in[4];
  const float* W       = (const float*)d_in[5];
  const float* M       = (const float*)d_in[6];
  const float* U       = (const float*)d_in[7];
  const float* V       = (const float*)d_in[8];
  const float* W1      = (const float*)d_in[9];
  const float* b1      = (const float*)d_in[10];
  const float* W2      = (const float*)d_in[11];
  const float* b2      = (const float*)d_in[12];
  float* out           = (float*)d_out;

  float* E = (float*)d_ws;                               // 2000*128 f32
  float* X = E + (size_t)G_N * D;                        // 2000*128 f32
  unsigned int* P = (unsigned int*)(X + (size_t)G_N * D); // 10000*64 uints (bf16 x2)
  unsigned int* Q = P + (size_t)NT_N * 64;

  k0_pq<<<dim3((NT_N + 63) / 64, 2), 256, 0, stream>>>(impact, W, M, P, Q);
  k1_gather<<<G_N, 256, 0, stream>>>(node_type, nbr_type,
                                     (const uint4*)P, (const uint4*)Q, E);
  k3_ext<<<G_N / 2, 256, 0, stream>>>(ext_nbr, E, U, V, X);
  k4_mlp<<<B_N / 2, 256, 0, stream>>>(batch, X, W1, b1, W2, b2, out);
}

// Round 5
// 134.777 us; speedup vs baseline: 1.6710x; 1.1321x over previous
//
#include <hip/hip_runtime.h>

typedef __bf16 bf16x8 __attribute__((ext_vector_type(8)));
typedef float f32x4 __attribute__((ext_vector_type(4)));

#define G_N 2000
#define K_N 64
#define DEG_INN 8
#define DEG_EXTN 16
#define B_N 1024
#define D 128
#define NT_N 10000

__device__ __forceinline__ float bflo(unsigned int u) { return __uint_as_float(u << 16); }
__device__ __forceinline__ float bfhi(unsigned int u) { return __uint_as_float(u & 0xffff0000u); }
__device__ __forceinline__ unsigned short f2bf(float f) {
  unsigned int u = __float_as_uint(f);
  u += 0x7fffu + ((u >> 16) & 1u);
  return (unsigned short)(u >> 16);
}
__device__ __forceinline__ unsigned int pack2bf(float lo, float hi) {
  return ((unsigned int)f2bf(hi) << 16) | (unsigned int)f2bf(lo);
}

// ---------------- K0: P=impact@W^T, Q=impact@M^T (bf16) + transposed tables --
// grid (157,3): y=0 -> P, y=1 -> Q, y=2 (x<64) -> Ut/Vt/W1t bf16 transposes.
constexpr int LD1 = 136;

__global__ __launch_bounds__(256)
void k0_prep(const float* __restrict__ impact,
             const float* __restrict__ Wm, const float* __restrict__ Mm,
             const float* __restrict__ U, const float* __restrict__ V,
             const float* __restrict__ W1,
             unsigned int* __restrict__ P, unsigned int* __restrict__ Q,
             unsigned int* __restrict__ Ut, unsigned int* __restrict__ Vt,
             unsigned int* __restrict__ W1t)
{
  __shared__ __align__(16) unsigned short Bs[128 * LD1];
  __shared__ __align__(16) unsigned short As[64 * LD1];

  const int tid = threadIdx.x;

  if (blockIdx.y == 2) {
    if (blockIdx.x >= 64) return;
    const int t = blockIdx.x * 256 + tid;       // [0, 16384)
    if (t < 8192) {                              // Ut/Vt: k = t>>6 in [0,128), jc = t&63
      int k = t >> 6, jc = t & 63;
      Ut[t] = pack2bf(U[(size_t)(2 * jc) * D + k], U[(size_t)(2 * jc + 1) * D + k]);
      Vt[t] = pack2bf(V[(size_t)(2 * jc) * D + k], V[(size_t)(2 * jc + 1) * D + k]);
    }
    {                                            // W1t: k = t>>6 in [0,256), jc = t&63
      int k = t >> 6, jc = t & 63;
      W1t[t] = pack2bf(W1[(size_t)(2 * jc) * 256 + k], W1[(size_t)(2 * jc + 1) * 256 + k]);
    }
    return;
  }

  const int rowbase = blockIdx.x * 64;
  const float* Bsrc = blockIdx.y ? Mm : Wm;
  unsigned int* dst = blockIdx.y ? Q : P;
  const int wave = tid >> 6, lane = tid & 63;

  for (int i = tid; i < 128 * 32; i += 256) {
    int row = i >> 5, c4 = i & 31;
    float4 v = ((const float4*)Bsrc)[row * 32 + c4];
    *(unsigned int*)(Bs + row * LD1 + c4 * 4)     = pack2bf(v.x, v.y);
    *(unsigned int*)(Bs + row * LD1 + c4 * 4 + 2) = pack2bf(v.z, v.w);
  }
  for (int i = tid; i < 64 * 32; i += 256) {
    int r = i >> 5, c4 = i & 31;
    int gr = rowbase + r; if (gr > NT_N - 1) gr = NT_N - 1;
    float4 v = ((const float4*)impact)[(size_t)gr * 32 + c4];
    *(unsigned int*)(As + r * LD1 + c4 * 4)     = pack2bf(v.x, v.y);
    *(unsigned int*)(As + r * LD1 + c4 * 4 + 2) = pack2bf(v.z, v.w);
  }
  __syncthreads();

  f32x4 acc[8];
  #pragma unroll
  for (int n = 0; n < 8; ++n) acc[n] = (f32x4){0.f, 0.f, 0.f, 0.f};
  const int qk   = (lane >> 4) * 8;
  const int arow = wave * 16 + (lane & 15);
  #pragma unroll
  for (int kk = 0; kk < 4; ++kk) {
    bf16x8 af = *(const bf16x8*)(As + arow * LD1 + kk * 32 + qk);
    #pragma unroll
    for (int n = 0; n < 8; ++n) {
      bf16x8 bfr = *(const bf16x8*)(Bs + (n * 16 + (lane & 15)) * LD1 + kk * 32 + qk);
      acc[n] = __builtin_amdgcn_mfma_f32_16x16x32_bf16(af, bfr, acc[n], 0, 0, 0);
    }
  }
  __syncthreads();

  const int quad = lane >> 4, c = lane & 15;
  #pragma unroll
  for (int n = 0; n < 8; ++n)
    #pragma unroll
    for (int reg = 0; reg < 4; ++reg)
      As[(wave * 16 + quad * 4 + reg) * LD1 + n * 16 + c] = f2bf(acc[n][reg]);
  __syncthreads();

  for (int i = tid; i < 64 * 32; i += 256) {
    int r = i >> 5, cc = i & 31;
    int gr = rowbase + r;
    if (gr < NT_N) {
      dst[(size_t)gr * 64 + cc * 2]     = *(unsigned int*)(As + r * LD1 + cc * 4);
      dst[(size_t)gr * 64 + cc * 2 + 1] = *(unsigned int*)(As + r * LD1 + cc * 4 + 2);
    }
  }
}

// ---------------- K1: gather-relu-reduce + softmax -> E ----------------------
__global__ __launch_bounds__(256)
void k1_gather(const int* __restrict__ node_type, const int* __restrict__ nbr_type,
               const uint4* __restrict__ P, const uint4* __restrict__ Q,
               float* __restrict__ E)
{
  __shared__ int nts[64];
  __shared__ int nbs[512];
  __shared__ float rg[16][132];
  __shared__ float pg[128];

  const int g    = blockIdx.x;
  const int tid  = threadIdx.x;
  const int wave = tid >> 6, lane = tid & 63;
  const int slot = lane >> 4, cl = lane & 15;

  if (tid < 64) nts[tid] = node_type[g * K_N + tid];
  nbs[tid]       = nbr_type[(size_t)g * 512 + tid];
  nbs[256 + tid] = nbr_type[(size_t)g * 512 + 256 + tid];
  __syncthreads();

  float acc[8];
  #pragma unroll
  for (int i = 0; i < 8; ++i) acc[i] = 0.f;

  for (int it = 0; it < 4; ++it) {
    const int r = wave * 16 + it * 4 + slot;
    uint4 sv = P[(size_t)nts[r] * 16 + cl];
    float rv[8];
    rv[0] = bflo(sv.x); rv[1] = bfhi(sv.x); rv[2] = bflo(sv.y); rv[3] = bfhi(sv.y);
    rv[4] = bflo(sv.z); rv[5] = bfhi(sv.z); rv[6] = bflo(sv.w); rv[7] = bfhi(sv.w);
    const int* nb = nbs + r * DEG_INN;
    #pragma unroll
    for (int d = 0; d < DEG_INN; ++d) {
      uint4 qv = Q[(size_t)nb[d] * 16 + cl];
      rv[0] += bflo(qv.x); rv[1] += bfhi(qv.x); rv[2] += bflo(qv.y); rv[3] += bfhi(qv.y);
      rv[4] += bflo(qv.z); rv[5] += bfhi(qv.z); rv[6] += bflo(qv.w); rv[7] += bfhi(qv.w);
    }
    #pragma unroll
    for (int i = 0; i < 8; ++i) acc[i] += fmaxf(rv[i], 0.f);
  }

  const int grp = wave * 4 + slot;
  #pragma unroll
  for (int i = 0; i < 8; ++i) rg[grp][cl * 8 + i] = acc[i];
  __syncthreads();

  if (tid < 128) {
    float s = 0.f;
    #pragma unroll
    for (int q = 0; q < 16; ++q) s += rg[q][tid];
    pg[tid] = s;
  }
  __syncthreads();

  if (wave == 0) {
    float v0 = pg[lane], v1 = pg[64 + lane];
    float mx = fmaxf(v0, v1);
    #pragma unroll
    for (int o = 32; o; o >>= 1) mx = fmaxf(mx, __shfl_xor(mx, o, 64));
    float e0 = __expf(v0 - mx), e1 = __expf(v1 - mx);
    float s = e0 + e1;
    #pragma unroll
    for (int o = 32; o; o >>= 1) s += __shfl_xor(s, o, 64);
    float inv = 1.f / s;
    E[(size_t)g * D + lane]      = e0 * inv;
    E[(size_t)g * D + 64 + lane] = e1 * inv;
  }
}

// ---------------- K3: ext = E@U^T + Esum@V^T ; X = softmax(relu(ext)) --------
// 1 graph/block. grp = {U,V} x {k-half}; coalesced transposed-table reads.
__global__ __launch_bounds__(256)
void k3_ext(const int* __restrict__ ext_nbr, const float* __restrict__ E,
            const unsigned int* __restrict__ Ut, const unsigned int* __restrict__ Vt,
            float* __restrict__ X)
{
  __shared__ float Ev[128], Es[128];
  __shared__ float p0[4][64], p1[4][64];
  __shared__ float scr[8];
  __shared__ int en[16];

  const int g   = blockIdx.x;
  const int tid = threadIdx.x;
  const int jc  = tid & 63, grp = tid >> 6;
  const int lane = tid & 63, wv = tid >> 6;

  if (tid < 16) en[tid] = ext_nbr[g * DEG_EXTN + tid];
  __syncthreads();

  if (tid < 128) {
    Ev[tid] = E[(size_t)g * D + tid];
  } else {
    const int j = tid - 128;
    float a = 0.f;
    #pragma unroll
    for (int d = 0; d < DEG_EXTN; ++d) a += E[(size_t)en[d] * D + j];
    Es[j] = a;
  }
  __syncthreads();

  const unsigned int* T = (grp & 2) ? Vt : Ut;
  const float* act      = (grp & 2) ? Es : Ev;
  const int k0 = (grp & 1) * 64;
  float s0 = 0.f, s1 = 0.f;
  #pragma unroll 16
  for (int k = 0; k < 64; ++k) {
    unsigned int uu = T[(k0 + k) * 64 + jc];
    float a = act[k0 + k];
    s0 += bflo(uu) * a; s1 += bfhi(uu) * a;
  }
  p0[grp][jc] = s0; p1[grp][jc] = s1;
  __syncthreads();

  float r = 0.f, e = 0.f;
  if (tid < 128) {
    const int jc2 = tid >> 1;
    float v = (tid & 1) ? (p1[0][jc2] + p1[1][jc2] + p1[2][jc2] + p1[3][jc2])
                        : (p0[0][jc2] + p0[1][jc2] + p0[2][jc2] + p0[3][jc2]);
    r = fmaxf(v, 0.f);
    float mx = r;
    #pragma unroll
    for (int o = 32; o; o >>= 1) mx = fmaxf(mx, __shfl_xor(mx, o, 64));
    if (lane == 0) scr[wv] = mx;
  }
  __syncthreads();
  if (tid < 128) {
    float mx = fmaxf(scr[0], scr[1]);
    e = __expf(r - mx);
    float sm = e;
    #pragma unroll
    for (int o = 32; o; o >>= 1) sm += __shfl_xor(sm, o, 64);
    if (lane == 0) scr[4 + wv] = sm;
  }
  __syncthreads();
  if (tid < 128) X[(size_t)g * D + tid] = e / (scr[4] + scr[5]);
}

// ---------------- K4: final MLP + 2-way softmax ------------------------------
__global__ __launch_bounds__(256)
void k4_mlp(const int* __restrict__ batch, const float* __restrict__ Xv,
            const unsigned int* __restrict__ W1t, const float* __restrict__ b1,
            const float* __restrict__ W2, const float* __restrict__ b2,
            float* __restrict__ out)
{
  __shared__ float feat[256];
  __shared__ float q0[4][64], q1[4][64];
  __shared__ float hv[128];
  __shared__ float scr[2];

  const int tid = threadIdx.x;
  const int jc = tid & 63, grp = tid >> 6;
  const int lane = tid & 63, wv = tid >> 6;

  for (int it = 0; it < 2; ++it) {
    const int b = blockIdx.x * 2 + it;
    const int i1 = batch[2 * b], i2 = batch[2 * b + 1];
    if (tid < 128) {
      float e1 = Xv[(size_t)i1 * D + tid], e2 = Xv[(size_t)i2 * D + tid];
      feat[tid]       = e1 * e2;
      feat[128 + tid] = e1 + e2;
    }
    __syncthreads();

    float s0 = 0.f, s1 = 0.f;
    #pragma unroll 16
    for (int k = 0; k < 64; ++k) {
      unsigned int uu = W1t[(grp * 64 + k) * 64 + jc];
      float a = feat[grp * 64 + k];
      s0 += bflo(uu) * a; s1 += bfhi(uu) * a;
    }
    q0[grp][jc] = s0; q1[grp][jc] = s1;
    __syncthreads();

    if (tid < 128) {
      const int jc2 = tid >> 1;
      float h = (tid & 1) ? (q1[0][jc2] + q1[1][jc2] + q1[2][jc2] + q1[3][jc2])
                          : (q0[0][jc2] + q0[1][jc2] + q0[2][jc2] + q0[3][jc2]);
      hv[tid] = fmaxf(h + b1[tid], 0.f);
    }
    __syncthreads();

    if (wv < 2) {
      float p = W2[wv * 128 + lane] * hv[lane]
              + W2[wv * 128 + 64 + lane] * hv[64 + lane];
      #pragma unroll
      for (int o = 32; o; o >>= 1) p += __shfl_xor(p, o, 64);
      if (lane == 0) scr[wv] = p + b2[wv];
    }
    __syncthreads();
    if (tid == 0) {
      float r0 = scr[0], r1 = scr[1];
      float m = fmaxf(r0, r1);
      float e0 = __expf(r0 - m), e1 = __expf(r1 - m);
      float inv = 1.f / (e0 + e1);
      out[2 * b]     = e0 * inv;
      out[2 * b + 1] = e1 * inv;
    }
    __syncthreads();
  }
}

// ---------------- launch -----------------------------------------------------
extern "C" void kernel_launch(void* const* d_in, const int* in_sizes, int n_in,
                              void* d_out, int out_size, void* d_ws, size_t ws_size,
                              hipStream_t stream) {
  const int* batch     = (const int*)d_in[0];
  const int* node_type = (const int*)d_in[1];
  const int* nbr_type  = (const int*)d_in[2];
  const int* ext_nbr   = (const int*)d_in[3];
  const float* impact  = (const float*)d_in[4];
  const float* W       = (const float*)d_in[5];
  const float* M       = (const float*)d_in[6];
  const float* U       = (const float*)d_in[7];
  const float* V       = (const float*)d_in[8];
  const float* W1      = (const float*)d_in[9];
  const float* b1      = (const float*)d_in[10];
  const float* W2      = (const float*)d_in[11];
  const float* b2      = (const float*)d_in[12];
  float* out           = (float*)d_out;

  float* E = (float*)d_ws;                                // 2000*128
  float* X = E + (size_t)G_N * D;                         // 2000*128
  unsigned int* P   = (unsigned int*)(X + (size_t)G_N * D); // 10000*64
  unsigned int* Q   = P + (size_t)NT_N * 64;               // 10000*64
  unsigned int* Ut  = Q + (size_t)NT_N * 64;               // 8192
  unsigned int* Vt  = Ut + 8192;                           // 8192
  unsigned int* W1t = Vt + 8192;                           // 16384

  k0_prep<<<dim3((NT_N + 63) / 64, 3), 256, 0, stream>>>(impact, W, M, U, V, W1,
                                                         P, Q, Ut, Vt, W1t);
  k1_gather<<<G_N, 256, 0, stream>>>(node_type, nbr_type,
                                     (const uint4*)P, (const uint4*)Q, E);
  k3_ext<<<G_N, 256, 0, stream>>>(ext_nbr, E, Ut, Vt, X);
  k4_mlp<<<B_N / 2, 256, 0, stream>>>(batch, X, W1t, b1, W2, b2, out);
}